// Round 11
// baseline (499.245 us; speedup 1.0000x reference)
//
#include <hip/hip_runtime.h>
#include <hip/hip_bf16.h>
#include <hip/hip_fp16.h>

#define D 128
#define NL 3
#define NODE_SH 8            // 256 nodes per bucket
#define NB_MAX 512
#define BIN_CHUNK 4096

typedef __attribute__((ext_vector_type(8))) short short8;
typedef __attribute__((ext_vector_type(8))) _Float16 half8;
typedef __attribute__((ext_vector_type(4))) float f32x4;

static inline size_t align256(size_t x){ return (x + 255) & ~(size_t)255; }

// ---------------- embedding gather: xh[n] = fp16(z_table[z[n]]) ----------------
__global__ __launch_bounds__(256) void k_embed(const int* __restrict__ z, const float* __restrict__ zt,
                                               __half* __restrict__ xh, int N){
    int i = blockIdx.x * blockDim.x + threadIdx.x;   // over N*32 groups of 4 elems
    int n = i >> 5, q = i & 31;
    if (n >= N) return;
    float4 v = *(const float4*)&zt[(size_t)z[n] * D + q * 4];
    __half2 p0 = __floats2half2_rn(v.x, v.y);
    __half2 p1 = __floats2half2_rn(v.z, v.w);
    uint2 u;
    u.x = *reinterpret_cast<unsigned*>(&p0);
    u.y = *reinterpret_cast<unsigned*>(&p1);
    *(uint2*)&xh[(size_t)n * D + q * 4] = u;
}

// ---------------- bucket-grain edge histogram ----------------
__global__ __launch_bounds__(256) void k_bcount(const int* __restrict__ dst, int* __restrict__ bcnt,
                                                int E, int NB){
    __shared__ int h[NB_MAX];
    const int t = threadIdx.x;
    for (int b = t; b < NB_MAX; b += 256) h[b] = 0;
    __syncthreads();
    const int stride = gridDim.x * 256;
    for (int e = blockIdx.x * 256 + t; e < E; e += stride)
        atomicAdd(&h[dst[e] >> NODE_SH], 1);
    __syncthreads();
    for (int b = t; b < NB; b += 256){
        int v = h[b];
        if (v) atomicAdd(&bcnt[b], v);
    }
}

// ---------------- bucket scan: gbase = excl-scan(bcnt), init gcur, offs[N]=E ----------------
__global__ __launch_bounds__(512) void k_bscan(const int* __restrict__ bcnt, int* __restrict__ gbase,
                                               int* __restrict__ gcur, int* __restrict__ offs,
                                               int NB, int N, int E){
    __shared__ int s[512];
    int t = threadIdx.x;
    int v = (t < NB) ? bcnt[t] : 0;
    s[t] = v; __syncthreads();
    for (int st = 1; st < 512; st <<= 1){
        int u = (t >= st) ? s[t - st] : 0;
        __syncthreads();
        s[t] += u;
        __syncthreads();
    }
    if (t < NB){
        int base = s[t] - v;      // exclusive
        gbase[t] = base;
        gcur[t] = base;
    }
    if (t == 0){ gbase[NB] = E; offs[N] = E; }
}

// ---------------- pass A: bin edges by dst-bucket with LDS reorder ----------------
__global__ __launch_bounds__(256) void k_binA(const int* __restrict__ src, const int* __restrict__ dst,
                                              int* __restrict__ gcur, int* __restrict__ ebuf2,
                                              int E, int NB){
    __shared__ int s_hist[NB_MAX];
    __shared__ int s_lofs[NB_MAX];
    __shared__ int s_delta[NB_MAX];
    __shared__ int s_pack[BIN_CHUNK];
    __shared__ int s_gdst[BIN_CHUNK];
    __shared__ int s_scan[256];
    const int t = threadIdx.x;
    const int e0 = blockIdx.x * BIN_CHUNK;
    for (int b = t; b < NB_MAX; b += 256) s_hist[b] = 0;
    __syncthreads();
    int my_pack[16], my_b[16], my_rank[16];
    #pragma unroll
    for (int i = 0; i < 16; ++i){
        int e = e0 + i * 256 + t;
        if (e < E){
            int s = src[e], d = dst[e];
            int b = d >> NODE_SH;
            my_pack[i] = s | ((d & 255) << 17);
            my_b[i] = b;
            my_rank[i] = atomicAdd(&s_hist[b], 1);
        } else my_b[i] = -1;
    }
    __syncthreads();
    int h0 = s_hist[2 * t], h1 = s_hist[2 * t + 1];
    int sum2 = h0 + h1;
    s_scan[t] = sum2;
    __syncthreads();
    for (int st = 1; st < 256; st <<= 1){
        int v = (t >= st) ? s_scan[t - st] : 0;
        __syncthreads();
        s_scan[t] += v;
        __syncthreads();
    }
    int excl = s_scan[t] - sum2;
    s_lofs[2 * t] = excl;
    s_lofs[2 * t + 1] = excl + h0;
    __syncthreads();
    for (int b = t; b < NB; b += 256){
        int h = s_hist[b];
        int base = (h > 0) ? atomicAdd(&gcur[b], h) : 0;
        s_delta[b] = base - s_lofs[b];
    }
    __syncthreads();
    #pragma unroll
    for (int i = 0; i < 16; ++i){
        if (my_b[i] >= 0){
            int j = s_lofs[my_b[i]] + my_rank[i];
            s_pack[j] = my_pack[i];
            s_gdst[j] = j + s_delta[my_b[i]];
        }
    }
    __syncthreads();
    const int cnt = min(BIN_CHUNK, E - e0);
    for (int j = t; j < cnt; j += 256)
        ebuf2[s_gdst[j]] = s_pack[j];
}

// ---------------- pass B: per-bucket node-degree + CSR fill ----------------
__global__ __launch_bounds__(256) void k_binB(const int* __restrict__ ebuf2, const int* __restrict__ gbase,
                                              int* __restrict__ ebuf, int* __restrict__ offs,
                                              float* __restrict__ invdeg, int N){
    __shared__ int cnt[256];
    __shared__ int lcur[256];
    __shared__ int s_scan[256];
    const int b = blockIdx.x, t = threadIdx.x;
    const int n0 = b << NODE_SH;
    const int rs = gbase[b], re = gbase[b + 1];
    cnt[t] = 0;
    __syncthreads();
    for (int i = rs + t; i < re; i += 256)
        atomicAdd(&cnt[ebuf2[i] >> 17], 1);
    __syncthreads();
    const int c = cnt[t];
    s_scan[t] = c;
    __syncthreads();
    for (int st = 1; st < 256; st <<= 1){
        int u = (t >= st) ? s_scan[t - st] : 0;
        __syncthreads();
        s_scan[t] += u;
        __syncthreads();
    }
    const int excl = s_scan[t] - c;
    lcur[t] = rs + excl;
    if (n0 + t < N){
        offs[n0 + t]   = rs + excl;
        invdeg[n0 + t] = 1.0f / (float)max(c, 1);
    }
    __syncthreads();
    for (int i = rs + t; i < re; i += 256){
        int v = ebuf2[i];
        int p = atomicAdd(&lcur[v >> 17], 1);
        ebuf[p] = v & 0x1FFFF;
    }
}

// ---------------- segment starts ----------------
__global__ __launch_bounds__(256) void k_centers(const int* __restrict__ batch, int* __restrict__ centers, int N){
    int n = blockIdx.x * blockDim.x + threadIdx.x;
    if (n < N && (n == 0 || batch[n] != batch[n - 1])) centers[batch[n]] = n;
}

// ---------------- weight prep ----------------
// WFh/WFl: fp16 2-term split of W, MFMA B-fragments in wave-contiguous order
// [l][ks][fn][lane][8 halves]; frag elem j: col = fn*16+(lane&15), k = ks*32+(lane>>4)*8+j
__global__ __launch_bounds__(256) void k_prepW(const float* __restrict__ Wl, const float* __restrict__ Wr,
                                               const float* __restrict__ W1, float* __restrict__ W1T,
                                               __half* __restrict__ WFh, __half* __restrict__ WFl){
    int i = blockIdx.x * blockDim.x + threadIdx.x;
    if (i < NL * 8 * 8 * 64){
        int lane = i & 63;
        int r = i >> 6;
        int fn = r & 7; r >>= 3;
        int ks = r & 7; r >>= 3;
        int l = r;
        int col = fn * 16 + (lane & 15);
        int k0 = ks * 32 + (lane >> 4) * 8;
        __half hh[8], ll[8];
        #pragma unroll
        for (int j = 0; j < 8; ++j){
            int k = k0 + j;
            float w = (k < D) ? Wl[(size_t)l * D * D + col * D + k]
                              : Wr[(size_t)l * D * D + col * D + (k - D)];
            __half h = __float2half(w);
            hh[j] = h;
            ll[j] = __float2half(w - __half2float(h));
        }
        #pragma unroll
        for (int j = 0; j < 8; ++j){
            WFh[(size_t)i * 8 + j] = hh[j];
            WFl[(size_t)i * 8 + j] = ll[j];
        }
    }
    if (i < D * D){ int k = i / D, d = i % D; W1T[i] = W1[d * D + k]; }
}

// ---------------- mean aggregation: gather fp16 rows, fp32 accumulate, fp16 out ----------
static __device__ inline void acc_h4(float4& a, uint2 u){
    __half2 h0 = *reinterpret_cast<__half2*>(&u.x);
    __half2 h1 = *reinterpret_cast<__half2*>(&u.y);
    float2 f0 = __half22float2(h0);
    float2 f1 = __half22float2(h1);
    a.x += f0.x; a.y += f0.y; a.z += f1.x; a.w += f1.y;
}

__global__ __launch_bounds__(256) void k_agg(const __half* __restrict__ xh, const int* __restrict__ ebuf,
                                             const int* __restrict__ offs, const float* __restrict__ invdeg,
                                             __half* __restrict__ aggh, int N){
    int node = blockIdx.x * 8 + (threadIdx.x >> 5);
    if (node >= N) return;
    int lane = threadIdx.x & 31;
    int s = offs[node], e = offs[node + 1];
    float4 a0 = make_float4(0.f,0.f,0.f,0.f), a1 = a0, a2 = a0, a3 = a0;
    int i = s;
    for (; i + 4 <= e; i += 4){
        int nb0 = ebuf[i], nb1 = ebuf[i+1], nb2 = ebuf[i+2], nb3 = ebuf[i+3];
        uint2 u0 = *(const uint2*)&xh[(size_t)nb0 * D + lane * 4];
        uint2 u1 = *(const uint2*)&xh[(size_t)nb1 * D + lane * 4];
        uint2 u2 = *(const uint2*)&xh[(size_t)nb2 * D + lane * 4];
        uint2 u3 = *(const uint2*)&xh[(size_t)nb3 * D + lane * 4];
        acc_h4(a0, u0); acc_h4(a1, u1); acc_h4(a2, u2); acc_h4(a3, u3);
    }
    for (; i < e; ++i){
        uint2 u = *(const uint2*)&xh[(size_t)ebuf[i] * D + lane * 4];
        acc_h4(a0, u);
    }
    a0.x += a1.x + a2.x + a3.x;
    a0.y += a1.y + a2.y + a3.y;
    a0.z += a1.z + a2.z + a3.z;
    a0.w += a1.w + a2.w + a3.w;
    float sc = invdeg[node];
    __half2 p0 = __floats2half2_rn(a0.x * sc, a0.y * sc);
    __half2 p1 = __floats2half2_rn(a0.z * sc, a0.w * sc);
    uint2 u;
    u.x = *reinterpret_cast<unsigned*>(&p0);
    u.y = *reinterpret_cast<unsigned*>(&p1);
    *(uint2*)&aggh[(size_t)node * D + lane * 4] = u;
}

// ---------------- fused dense via fp16 MFMA (2-term W split), 2 row-tiles/wave ----------
// Out = [aggh | xh] (N,256) @ (Wh+Wl) (256,128) + bias.
// A-operands are EXACT fp16 (no conversion); W split wh+wl gives ~2^-22 weight precision.
// 2 MFMAs per fragment (vs 3 for split-bf16), zero per-element VALU conversion.
// Intermediate layers (FINAL=false): relu + write fp16 shadow only.
// Final layer (FINAL=true): write fp32 for the head.
template<bool FINAL>
__global__ __launch_bounds__(256) void k_dense_mfma(const __half* __restrict__ Agh, const __half* __restrict__ Xh,
                                                    const __half* __restrict__ WFh, const __half* __restrict__ WFl,
                                                    const float* __restrict__ bias,
                                                    float* __restrict__ Out, __half* __restrict__ XhOut, int N){
    const int wave = threadIdx.x >> 6;
    const int lane = threadIdx.x & 63;
    const int l15  = lane & 15;
    const int kg   = lane >> 4;          // 0..3
    const int rbase = blockIdx.x * 128 + wave * 32;

    f32x4 acc[2][8];
    #pragma unroll
    for (int t = 0; t < 2; ++t)
        #pragma unroll
        for (int fn = 0; fn < 8; ++fn) acc[t][fn] = (f32x4){0.f, 0.f, 0.f, 0.f};

    #pragma unroll
    for (int ks = 0; ks < 8; ++ks){
        const __half* S = (ks < 4) ? Agh : Xh;
        const int ko = (ks & 3) * 32 + kg * 8;
        half8 av[2];
        #pragma unroll
        for (int t = 0; t < 2; ++t){
            int row = rbase + t * 16 + l15;
            row = min(row, N - 1);
            av[t] = *(const half8*)&S[(size_t)row * D + ko];
        }
        #pragma unroll
        for (int fn = 0; fn < 8; ++fn){
            const size_t fo = ((size_t)(ks * 8 + fn) * 64 + lane) * 8;
            const half8 bh = *(const half8*)&WFh[fo];
            const half8 bl = *(const half8*)&WFl[fo];
            #pragma unroll
            for (int t = 0; t < 2; ++t){
                acc[t][fn] = __builtin_amdgcn_mfma_f32_16x16x32_f16(av[t], bh, acc[t][fn], 0, 0, 0);
                acc[t][fn] = __builtin_amdgcn_mfma_f32_16x16x32_f16(av[t], bl, acc[t][fn], 0, 0, 0);
            }
        }
    }
    // epilogue: C/D layout col=lane&15, row=(lane>>4)*4+reg  [m89 verified]
    #pragma unroll
    for (int t = 0; t < 2; ++t){
        const int rb = rbase + t * 16 + (kg << 2);
        #pragma unroll
        for (int fn = 0; fn < 8; ++fn){
            const int col = fn * 16 + l15;
            const float bv = bias[col];
            #pragma unroll
            for (int r = 0; r < 4; ++r){
                const int orow = rb + r;
                if (orow < N){
                    float v = acc[t][fn][r] + bv;
                    if (!FINAL){
                        v = fmaxf(v, 0.f);
                        XhOut[(size_t)orow * D + col] = __float2half(v);
                    } else {
                        Out[(size_t)orow * D + col] = v;
                    }
                }
            }
        }
    }
}

// ---------------- head: out[g] = W2 @ relu(W1 @ (x[c]*x[c+1]) + b1) + b2 ----------------
__global__ __launch_bounds__(128) void k_head(const float* __restrict__ x, const int* __restrict__ centers,
                                              const float* __restrict__ W1T, const float* __restrict__ b1,
                                              const float* __restrict__ W2, const float* __restrict__ b2,
                                              float* __restrict__ out){
    __shared__ float hs[D];
    __shared__ float red[D];
    int g = blockIdx.x; int d = threadIdx.x;
    int c = centers[g];
    hs[d] = x[(size_t)c * D + d] * x[(size_t)(c + 1) * D + d];
    __syncthreads();
    float acc = b1[d];
    #pragma unroll 8
    for (int k = 0; k < D; ++k) acc = fmaf(hs[k], W1T[k * D + d], acc);
    acc = fmaxf(acc, 0.f);
    red[d] = acc * W2[d];
    __syncthreads();
    for (int st = 64; st > 0; st >>= 1){
        if (d < st) red[d] += red[d + st];
        __syncthreads();
    }
    if (d == 0) out[g] = red[0] + b2[0];
}

extern "C" void kernel_launch(void* const* d_in, const int* in_sizes, int n_in,
                              void* d_out, int out_size, void* d_ws, size_t ws_size,
                              hipStream_t stream){
    const int*   z     = (const int*)  d_in[0];
    const int*   eidx  = (const int*)  d_in[1];
    const int*   batch = (const int*)  d_in[2];
    const float* zt    = (const float*)d_in[3];
    const float* Wl    = (const float*)d_in[4];
    const float* bl    = (const float*)d_in[5];
    const float* Wr    = (const float*)d_in[6];
    const float* W1    = (const float*)d_in[7];
    const float* b1    = (const float*)d_in[8];
    const float* W2    = (const float*)d_in[9];
    const float* b2    = (const float*)d_in[10];
    float* out = (float*)d_out;

    const int N = in_sizes[0];
    const int E = in_sizes[1] / 2;
    const int G = out_size;
    const int NB = (N + 255) >> NODE_SH;
    const int* src  = eidx;
    const int* dstp = eidx + E;

    char* p = (char*)d_ws;
    auto alloc = [&](size_t bytes){ char* r = p; p += align256(bytes); return r; };
    float*  xf     = (float*)alloc((size_t)N * D * 4);   // final-layer fp32 output (head input)
    __half* aggh   = (__half*)alloc((size_t)N * D * 2);
    __half* xha    = (__half*)alloc((size_t)N * D * 2);
    __half* xhb    = (__half*)alloc((size_t)N * D * 2);
    float* invdeg  = (float*)alloc((size_t)N * 4);
    int*   offs    = (int*)  alloc((size_t)(N + 1) * 4);
    int*   ebuf    = (int*)  alloc((size_t)E * 4);
    int*   ebuf2   = (int*)  alloc((size_t)E * 4);
    int*   centers = (int*)  alloc((size_t)G * 4);
    int*   bcnt    = (int*)  alloc((size_t)NB_MAX * 4);
    int*   gbase   = (int*)  alloc((size_t)(NB_MAX + 1) * 4);
    int*   gcur    = (int*)  alloc((size_t)NB_MAX * 4);
    float* W1T     = (float*)alloc((size_t)D * D * 4);
    __half* WFh    = (__half*)alloc((size_t)NL * 8 * 8 * 64 * 8 * 2);
    __half* WFl    = (__half*)alloc((size_t)NL * 8 * 8 * 64 * 8 * 2);
    (void)ws_size; (void)n_in;

    hipMemsetAsync(bcnt, 0, (size_t)NB_MAX * 4, stream);
    k_embed<<<(N * 32 + 255) / 256, 256, 0, stream>>>(z, zt, xha, N);
    k_bcount<<<512, 256, 0, stream>>>(dstp, bcnt, E, NB);
    k_bscan<<<1, 512, 0, stream>>>(bcnt, gbase, gcur, offs, NB, N, E);
    k_binA<<<(E + BIN_CHUNK - 1) / BIN_CHUNK, 256, 0, stream>>>(src, dstp, gcur, ebuf2, E, NB);
    k_binB<<<NB, 256, 0, stream>>>(ebuf2, gbase, ebuf, offs, invdeg, N);
    k_centers<<<(N + 255) / 256, 256, 0, stream>>>(batch, centers, N);
    k_prepW<<<64, 256, 0, stream>>>(Wl, Wr, W1, W1T, WFh, WFl);

    __half* xhc = xha; __half* xhn = xhb;
    for (int l = 0; l < NL; ++l){
        k_agg<<<(N + 7) / 8, 256, 0, stream>>>(xhc, ebuf, offs, invdeg, aggh, N);
        const __half* wh = WFh + (size_t)l * 8 * 8 * 64 * 8;
        const __half* wl = WFl + (size_t)l * 8 * 8 * 64 * 8;
        if (l < NL - 1)
            k_dense_mfma<false><<<(N + 127) / 128, 256, 0, stream>>>(aggh, xhc, wh, wl, bl + l * D, nullptr, xhn, N);
        else
            k_dense_mfma<true ><<<(N + 127) / 128, 256, 0, stream>>>(aggh, xhc, wh, wl, bl + l * D, xf, nullptr, N);
        __half* th = xhc; xhc = xhn; xhn = th;
    }
    k_head<<<G, 128, 0, stream>>>(xf, centers, W1T, b1, W2, b2, out);
}